// Round 5
// baseline (134.318 us; speedup 1.0000x reference)
//
#include <hip/hip_runtime.h>
#include <stdint.h>

#define SQ1_2 0.70710678118654752440f

// LDS map (floats): raw region = 16 chunks x 264 (8 pad floats/chunk to break
// bank alignment of the 256-float row-chunks); spec region = 64 records x 68
// (+4 pad floats/record). Total 8576 floats = 34.3 KB -> 4 blocks/CU.
#define RAW_CHUNK 264
#define SPEC_OFF  4224          // 16*264
#define SPEC_REC  68
#define LDS_FLOATS 8576         // 4224 + 64*68

// g(x) = sign(x) * log1p(|x|)
__device__ __forceinline__ float g_feat(float x) {
    return copysignf(__logf(1.0f + fabsf(x)), x);
}

// Real 8-point DFT. Input r[0..7]; output packed:
// o[0]=F0 (real), o[1]=F4 (real), o[2..3]=F1 (re,im), o[4..5]=F2, o[6..7]=F3.
__device__ __forceinline__ void rfft8(const float r[8], float o[8]) {
    float s0 = r[0] + r[4], d0 = r[0] - r[4];
    float s1 = r[1] + r[5], d1 = r[1] - r[5];
    float s2 = r[2] + r[6], d2 = r[2] - r[6];
    float s3 = r[3] + r[7], d3 = r[3] - r[7];
    float ss02 = s0 + s2, sd02 = s0 - s2;
    float ss13 = s1 + s3, sd13 = s1 - s3;
    float t1 = SQ1_2 * (d1 - d3);
    float t2 = SQ1_2 * (d1 + d3);
    o[0] = ss02 + ss13;       // F0
    o[1] = ss02 - ss13;       // F4
    o[2] = d0 + t1;           // F1r
    o[3] = -(d2 + t2);        // F1i
    o[4] = sd02;              // F2r
    o[5] = -sd13;             // F2i
    o[6] = d0 - t1;           // F3r
    o[7] = d2 - t2;           // F3i
}

// Complex 8-point DFT (DIT radix-2): inputs xr/xi[8], outputs Fr/Fi[8].
__device__ __forceinline__ void cfft8(const float xr[8], const float xi[8],
                                      float Fr[8], float Fi[8]) {
    float s0r = xr[0] + xr[4], s0i = xi[0] + xi[4], d0r = xr[0] - xr[4], d0i = xi[0] - xi[4];
    float s1r = xr[1] + xr[5], s1i = xi[1] + xi[5], d1r = xr[1] - xr[5], d1i = xi[1] - xi[5];
    float s2r = xr[2] + xr[6], s2i = xi[2] + xi[6], d2r = xr[2] - xr[6], d2i = xi[2] - xi[6];
    float s3r = xr[3] + xr[7], s3i = xi[3] + xi[7], d3r = xr[3] - xr[7], d3i = xi[3] - xi[7];
    float ss0r = s0r + s2r, ss0i = s0i + s2i, sd0r = s0r - s2r, sd0i = s0i - s2i;
    float ss1r = s1r + s3r, ss1i = s1i + s3i, sd1r = s1r - s3r, sd1i = s1i - s3i;
    Fr[0] = ss0r + ss1r; Fi[0] = ss0i + ss1i;
    Fr[4] = ss0r - ss1r; Fi[4] = ss0i - ss1i;
    Fr[2] = sd0r + sd1i; Fi[2] = sd0i - sd1r;   // sd0 - i*sd1
    Fr[6] = sd0r - sd1i; Fi[6] = sd0i + sd1r;   // sd0 + i*sd1
    float t1r = SQ1_2 * (d1r + d1i), t1i = SQ1_2 * (d1i - d1r);   // d1 * e^{-i pi/4}
    float t2r = d2i,                 t2i = -d2r;                  // d2 * (-i)
    float t3r = SQ1_2 * (d3i - d3r), t3i = -SQ1_2 * (d3r + d3i);  // d3 * e^{-i 3pi/4}
    float ts0r = d0r + t2r, ts0i = d0i + t2i, td0r = d0r - t2r, td0i = d0i - t2i;
    float ts1r = t1r + t3r, ts1i = t1i + t3i, td1r = t1r - t3r, td1i = t1i - t3i;
    Fr[1] = ts0r + ts1r; Fi[1] = ts0i + ts1i;
    Fr[5] = ts0r - ts1r; Fi[5] = ts0i - ts1i;
    Fr[3] = td0r + td1i; Fi[3] = td0i - td1r;
    Fr[7] = td0r - td1i; Fi[7] = td0i + td1r;
}

// Block = 256 threads, 32 patch-pairs.
// Phase A: async DMA (global_load_lds x16B) stages 16 KB of raw patch rows
//          (16 chunks of 1 KB: tensor T x row m, 32 consecutive patches each)
//          with NO dest VGPRs -> ~4 KB outstanding per wave -> BW-saturating.
// Phase B1: thread (pw,T,r2) row-FFTs rows 2r2,2r2+1 from LDS, writes packed
//           spectra to padded spec records.
// Phase B2: thread (pw,T,task) column-FFT + g + diff vs partner (tid^4).
__global__ __launch_bounds__(256, 4) void patchfft_stage_kernel(
        const float* __restrict__ in, const float* __restrict__ tgt,
        float* __restrict__ partial) {
    __shared__ float lds[LDS_FLOATS];
    __shared__ float wsum[4];
    const int tid = threadIdx.x;

    // ---------- phase A: DMA raw rows into LDS ----------
    {
        const int w    = tid >> 6;          // wave 0..3
        const int lane = tid & 63;
        const int p0 = blockIdx.x * 32;     // 32 consecutive patches; pw0 = 0 or 32
        const int pw0 = p0 & 63;
        const int ph  = (p0 >> 6) & 63;
        const int bc  = p0 >> 12;
        const long gbase = (long)bc * 262144 + (long)ph * 4096 + pw0 * 8;
        #pragma unroll
        for (int i = 0; i < 4; ++i) {
            const int k = w * 4 + i;        // chunk 0..15: T = k>>3, row m = k&7
            const int T = k >> 3;
            const int m = k & 7;
            const float* src = T ? tgt : in;
            const float* gp = src + gbase + (long)m * 512 + lane * 4;  // lane*16B
            // HW semantics: lane l's 16B -> ldsbase + l*16 (wave-uniform base)
            __builtin_amdgcn_global_load_lds(
                (const __attribute__((address_space(1))) void*)gp,
                (__attribute__((address_space(3))) void*)&lds[k * RAW_CHUNK],
                16, 0, 0);
        }
    }
    __syncthreads();   // drains vmcnt (DMA completion) + barrier

    const int pw = tid >> 3;         // pair 0..31
    const int T  = (tid >> 2) & 1;   // tensor
    const int rec = SPEC_OFF + (pw * 2 + T) * SPEC_REC;

    // ---------- phase B1: row FFTs LDS -> LDS ----------
    {
        const int r2 = tid & 3;      // rows 2r2, 2r2+1
        #pragma unroll
        for (int mm = 0; mm < 2; ++mm) {
            const int m = 2 * r2 + mm;
            const int rb = (T * 8 + m) * RAW_CHUNK + pw * 8;
            float r[8];
            #pragma unroll
            for (int j = 0; j < 4; ++j) {
                const int c = (r2 + j) & 3;  // rotate start: spreads LDS banks
                float2 z = *reinterpret_cast<const float2*>(&lds[rb + c * 2]);
                r[c * 2]     = z.x * 0.125f; // 1/sqrt(64): full ortho scale
                r[c * 2 + 1] = z.y * 0.125f;
            }
            float o[8];
            rfft8(r, o);
            float4* dst = reinterpret_cast<float4*>(&lds[rec + m * 8]);
            dst[0] = make_float4(o[0], o[1], o[2], o[3]);
            dst[1] = make_float4(o[4], o[5], o[6], o[7]);
        }
    }
    __syncthreads();

    // ---------- phase B2: column FFTs + features + diff ----------
    float loss;
    {
        const int task = tid & 3;    // partner lane = tid ^ 4 (other tensor)
        float zr[8], zi[8];
        #pragma unroll
        for (int m = 0; m < 8; ++m) {
            float2 z = *reinterpret_cast<const float2*>(&lds[rec + m * 8 + task * 2]);
            zr[m] = z.x;             // task0: col l=0; task l: row-F_l re
            zi[m] = z.y;             // task0: col l=4; task l: row-F_l im
        }
        float Fr[8], Fi[8];
        cfft8(zr, zi, Fr, Fi);

        float acc1 = 0.0f, acc2 = 0.0f;
        if (task == 0) {
            // Two real column spectra from one complex FFT:
            // F_c0[k] = (Z[k]+conj(Z[8-k]))/2, F_c1[k] = (Z[k]-conj(Z[8-k]))/(2i)
            // k=0,4 bins are real: F_c0 = Zr, F_c1 = Zi. Weight 1.
            float w0 = g_feat(Fr[0]), w1 = g_feat(Fr[4]);
            float w2 = g_feat(Fi[0]), w3 = g_feat(Fi[4]);
            float d0 = w0 - __shfl_xor(w0, 4, 64);
            float d1 = w1 - __shfl_xor(w1, 4, 64);
            float d2 = w2 - __shfl_xor(w2, 4, 64);
            float d3 = w3 - __shfl_xor(w3, 4, 64);
            acc1 = d0 * d0 + d1 * d1 + d2 * d2 + d3 * d3;
            #pragma unroll
            for (int k = 1; k <= 3; ++k) {   // weight-2 bins (conj partners implied)
                float v0 = 0.5f * (Fr[k] + Fr[8 - k]);   // F_c0[k] re
                float v1 = 0.5f * (Fi[k] - Fi[8 - k]);   // F_c0[k] im
                float v2 = 0.5f * (Fi[k] + Fi[8 - k]);   // F_c1[k] re
                float v3 = 0.5f * (Fr[k] - Fr[8 - k]);   // F_c1[k] im (sign dropped; g odd)
                float f0 = g_feat(v0), f1 = g_feat(v1), f2 = g_feat(v2), f3 = g_feat(v3);
                float e0 = f0 - __shfl_xor(f0, 4, 64);
                float e1 = f1 - __shfl_xor(f1, 4, 64);
                float e2 = f2 - __shfl_xor(f2, 4, 64);
                float e3 = f3 - __shfl_xor(f3, 4, 64);
                acc2 += e0 * e0 + e1 * e1 + e2 * e2 + e3 * e3;
            }
        } else {
            #pragma unroll
            for (int k = 0; k < 8; ++k) {    // complex column: all 8 bins weight 2
                float fr = g_feat(Fr[k]);
                float fi = g_feat(Fi[k]);
                float dr = fr - __shfl_xor(fr, 4, 64);
                float di = fi - __shfl_xor(fi, 4, 64);
                acc2 += dr * dr + di * di;
            }
        }
        loss = acc1 + 2.0f * acc2;
    }

    // wave reduce -> block reduce -> one atomic per block into 256 slots
    #pragma unroll
    for (int off = 32; off > 0; off >>= 1) loss += __shfl_down(loss, off, 64);
    if ((tid & 63) == 0) wsum[tid >> 6] = loss;
    __syncthreads();
    if (tid == 0) {
        atomicAdd(&partial[blockIdx.x & 255], wsum[0] + wsum[1] + wsum[2] + wsum[3]);
    }
}

__global__ void patchfft_final_kernel(const float* __restrict__ partial,
                                      float* __restrict__ out) {
    float s = partial[threadIdx.x] + partial[threadIdx.x + 64]
            + partial[threadIdx.x + 128] + partial[threadIdx.x + 192];
    #pragma unroll
    for (int off = 32; off > 0; off >>= 1) s += __shfl_down(s, off, 64);
    // mean over 12,582,912 elements; x0.5 because both tensor-halves compute
    // the identical diff^2
    if (threadIdx.x == 0) *out = s * (1.0f / 25165824.0f);
}

extern "C" void kernel_launch(void* const* d_in, const int* in_sizes, int n_in,
                              void* d_out, int out_size, void* d_ws, size_t ws_size,
                              hipStream_t stream) {
    const float* in  = (const float*)d_in[0];
    const float* tgt = (const float*)d_in[1];
    float* out = (float*)d_out;
    float* partial = (float*)d_ws;       // 256 floats of scratch
    (void)in_sizes; (void)n_in; (void)ws_size; (void)out_size;

    hipMemsetAsync(partial, 0, 256 * sizeof(float), stream);  // d_ws is poisoned
    // 196608 pairs / 32 per block
    patchfft_stage_kernel<<<6144, 256, 0, stream>>>(in, tgt, partial);
    patchfft_final_kernel<<<1, 64, 0, stream>>>(partial, out);
}

// Round 6
// 123.407 us; speedup vs baseline: 1.0884x; 1.0884x over previous
//
#include <hip/hip_runtime.h>
#include <stdint.h>

#define SQ1_2 0.70710678118654752440f

// g(x) = sign(x) * log1p(|x|)
__device__ __forceinline__ float g_feat(float x) {
    return copysignf(__logf(1.0f + fabsf(x)), x);
}

// Real 8-point DFT. Input r[0..7]; output packed:
// o[0]=F0 (real), o[1]=F4 (real), o[2..3]=F1 (re,im), o[4..5]=F2, o[6..7]=F3.
__device__ __forceinline__ void rfft8(const float r[8], float o[8]) {
    float s0 = r[0] + r[4], d0 = r[0] - r[4];
    float s1 = r[1] + r[5], d1 = r[1] - r[5];
    float s2 = r[2] + r[6], d2 = r[2] - r[6];
    float s3 = r[3] + r[7], d3 = r[3] - r[7];
    float ss02 = s0 + s2, sd02 = s0 - s2;
    float ss13 = s1 + s3, sd13 = s1 - s3;
    float t1 = SQ1_2 * (d1 - d3);
    float t2 = SQ1_2 * (d1 + d3);
    o[0] = ss02 + ss13;       // F0
    o[1] = ss02 - ss13;       // F4
    o[2] = d0 + t1;           // F1r
    o[3] = -(d2 + t2);        // F1i
    o[4] = sd02;              // F2r
    o[5] = -sd13;             // F2i
    o[6] = d0 - t1;           // F3r
    o[7] = d2 - t2;           // F3i
}

// Complex 8-point DFT (DIT radix-2): inputs xr/xi[8], outputs Fr/Fi[8].
__device__ __forceinline__ void cfft8(const float xr[8], const float xi[8],
                                      float Fr[8], float Fi[8]) {
    float s0r = xr[0] + xr[4], s0i = xi[0] + xi[4], d0r = xr[0] - xr[4], d0i = xi[0] - xi[4];
    float s1r = xr[1] + xr[5], s1i = xi[1] + xi[5], d1r = xr[1] - xr[5], d1i = xi[1] - xi[5];
    float s2r = xr[2] + xr[6], s2i = xi[2] + xi[6], d2r = xr[2] - xr[6], d2i = xi[2] - xi[6];
    float s3r = xr[3] + xr[7], s3i = xi[3] + xi[7], d3r = xr[3] - xr[7], d3i = xi[3] - xi[7];
    float ss0r = s0r + s2r, ss0i = s0i + s2i, sd0r = s0r - s2r, sd0i = s0i - s2i;
    float ss1r = s1r + s3r, ss1i = s1i + s3i, sd1r = s1r - s3r, sd1i = s1i - s3i;
    Fr[0] = ss0r + ss1r; Fi[0] = ss0i + ss1i;
    Fr[4] = ss0r - ss1r; Fi[4] = ss0i - ss1i;
    Fr[2] = sd0r + sd1i; Fi[2] = sd0i - sd1r;   // sd0 - i*sd1
    Fr[6] = sd0r - sd1i; Fi[6] = sd0i + sd1r;   // sd0 + i*sd1
    float t1r = SQ1_2 * (d1r + d1i), t1i = SQ1_2 * (d1i - d1r);   // d1 * e^{-i pi/4}
    float t2r = d2i,                 t2i = -d2r;                  // d2 * (-i)
    float t3r = SQ1_2 * (d3i - d3r), t3i = -SQ1_2 * (d3r + d3i);  // d3 * e^{-i 3pi/4}
    float ts0r = d0r + t2r, ts0i = d0i + t2i, td0r = d0r - t2r, td0i = d0i - t2i;
    float ts1r = t1r + t3r, ts1i = t1i + t3i, td1r = t1r - t3r, td1i = t1i - t3i;
    Fr[1] = ts0r + ts1r; Fi[1] = ts0i + ts1i;
    Fr[5] = ts0r - ts1r; Fi[5] = ts0i - ts1i;
    Fr[3] = td0r + td1i; Fi[3] = td0i - td1r;
    Fr[7] = td0r - td1i; Fi[7] = td0i + td1r;
}

// Block = ONE wave (64 threads) = 32 patch-pairs.
// Phase A: 16 x global_load_lds (16B/lane) stage 16 KB of raw rows (chunk =
//   tensor T x row m x 32 patches) with no dest VGPRs -> 16 KB in flight per
//   wave, BW-saturating.
// Phase B: fat thread — lane<32: input patch, lane>=32: target patch. Reads
//   its own 8 rows from LDS, full 2D FFT + g in registers (R2's validated
//   math), diffs via __shfl_xor(.,32). Zero cooperation tax, one barrier.
__global__ __launch_bounds__(64) void patchfft_stage_kernel(
        const float* __restrict__ in, const float* __restrict__ tgt,
        float* __restrict__ partial) {
    __shared__ float lds[4096];          // 16 chunks x 256 floats = 16 KB
    const int lane = threadIdx.x;        // 0..63

    const int p0 = blockIdx.x * 32;      // 32 consecutive patches
    const int pw0 = p0 & 63;             // 0 or 32
    const int ph  = (p0 >> 6) & 63;
    const int bc  = p0 >> 12;
    const long gbase = (long)bc * 262144 + (long)ph * 4096 + pw0 * 8;

    // ---------- phase A: DMA all raw rows of both tensors ----------
    #pragma unroll
    for (int c = 0; c < 16; ++c) {       // c = T*8 + m
        const int T = c >> 3;
        const int m = c & 7;
        const float* src = T ? tgt : in;
        const float* gp = src + gbase + (long)m * 512 + lane * 4;  // lane*16B
        __builtin_amdgcn_global_load_lds(
            (const __attribute__((address_space(1))) void*)gp,
            (__attribute__((address_space(3))) void*)&lds[c * 256],
            16, 0, 0);
    }
    __syncthreads();   // drains vmcnt (DMA completion)

    // ---------- phase B: fat-thread 2D FFT from LDS ----------
    const int Ts = lane >> 5;            // 0=input, 1=target
    const int q  = lane & 31;            // patch within block

    float v[64];
    #pragma unroll
    for (int m = 0; m < 8; ++m) {
        const float4* row = reinterpret_cast<const float4*>(&lds[(Ts * 8 + m) * 256 + q * 8]);
        float4 lo = row[0];
        float4 hi = row[1];
        float r[8] = {lo.x * 0.125f, lo.y * 0.125f, lo.z * 0.125f, lo.w * 0.125f,
                      hi.x * 0.125f, hi.y * 0.125f, hi.z * 0.125f, hi.w * 0.125f};
        rfft8(r, &v[m * 8]);
    }

    // Stage 2: column FFTs; diff against the partner half-wave as features
    // are produced. Both halves compute identical (d^2) -> 0.5 in divisor.
    float acc1 = 0.0f, acc2 = 0.0f;
    #pragma unroll
    for (int j = 0; j < 2; ++j) {                // real columns l=0 (j=0), l=4 (j=1)
        float c[8], o[8];
        #pragma unroll
        for (int m = 0; m < 8; ++m) c[m] = v[m * 8 + j];
        rfft8(c, o);
        #pragma unroll
        for (int k = 0; k < 8; ++k) {
            float fm = g_feat(o[k]);
            float d = fm - __shfl_xor(fm, 32, 64);
            if (k < 2) acc1 += d * d;            // k=0 and k=4 bins: weight 1
            else       acc2 += d * d;            // weight 2 (conj partner)
        }
    }
    #pragma unroll
    for (int l = 0; l < 3; ++l) {                // complex columns l=1..3, all weight 2
        float cr[8], ci[8], Fr[8], Fi[8];
        #pragma unroll
        for (int m = 0; m < 8; ++m) {
            cr[m] = v[m * 8 + 2 + 2 * l];
            ci[m] = v[m * 8 + 3 + 2 * l];
        }
        cfft8(cr, ci, Fr, Fi);
        #pragma unroll
        for (int k = 0; k < 8; ++k) {
            float fr = g_feat(Fr[k]);
            float fi = g_feat(Fi[k]);
            float dr = fr - __shfl_xor(fr, 32, 64);
            float di = fi - __shfl_xor(fi, 32, 64);
            acc2 += dr * dr + di * di;
        }
    }
    float loss = acc1 + 2.0f * acc2;

    // single-wave block: shuffle reduce, one atomic per block
    #pragma unroll
    for (int off = 32; off > 0; off >>= 1) loss += __shfl_down(loss, off, 64);
    if (lane == 0) {
        atomicAdd(&partial[blockIdx.x & 255], loss);
    }
}

__global__ void patchfft_final_kernel(const float* __restrict__ partial,
                                      float* __restrict__ out) {
    float s = partial[threadIdx.x] + partial[threadIdx.x + 64]
            + partial[threadIdx.x + 128] + partial[threadIdx.x + 192];
    #pragma unroll
    for (int off = 32; off > 0; off >>= 1) s += __shfl_down(s, off, 64);
    // mean over 12,582,912 elements; x0.5 because both tensor-halves compute
    // the identical diff^2
    if (threadIdx.x == 0) *out = s * (1.0f / 25165824.0f);
}

extern "C" void kernel_launch(void* const* d_in, const int* in_sizes, int n_in,
                              void* d_out, int out_size, void* d_ws, size_t ws_size,
                              hipStream_t stream) {
    const float* in  = (const float*)d_in[0];
    const float* tgt = (const float*)d_in[1];
    float* out = (float*)d_out;
    float* partial = (float*)d_ws;       // 256 floats of scratch
    (void)in_sizes; (void)n_in; (void)ws_size; (void)out_size;

    hipMemsetAsync(partial, 0, 256 * sizeof(float), stream);  // d_ws is poisoned
    // 196608 pairs / 32 per (single-wave) block
    patchfft_stage_kernel<<<6144, 64, 0, stream>>>(in, tgt, partial);
    patchfft_final_kernel<<<1, 64, 0, stream>>>(partial, out);
}